// Round 8
// baseline (942.890 us; speedup 1.0000x reference)
//
#include <hip/hip_runtime.h>
#include <hip/hip_bf16.h>

// Problem dims (fixed by reference)
constexpr int N_ = 64, C_ = 512, T_ = 1024;
constexpr int NT_ = N_ * T_;        // 65536 rows
constexpr int K_ = 1024;            // nb_code
constexpr int A_ = 512;             // attn_dim

// Output layout (floats, concatenated in return order)
constexpr size_t XD_OFF   = 0;                       // 33554432 floats
constexpr size_t SC_OFF   = (size_t)N_ * C_ * T_;    // 5 scalars
constexpr size_t CODE_OFF = SC_OFF + 5;              // 65536 code_idx as float
// NOTE: D~ (fp16 [NT][1024] = 134217728 B) EXACTLY fits the XD region of d_out.
// It is written by d_kernel, consumed by stats_kernel, then zq_kernel
// overwrites the region with x_d (stream-ordered, same launch).

// Workspace layout (floats)
// region0 (128 MB): xhT bf16 [NT][512] (first 64 MB); att bf16 [NT][1024]
//   aliases the same base — xhT is dead once stats_kernel (which writes att)
//   runs, and d_kernel (the only xhT reader) fully precedes it.
constexpr size_t MHT_OFF  = 33554432;                 // MhT bf16 [1024][512]
constexpr size_t MT_OFF   = MHT_OFF + 262144;         // MT fp32 [1024][512]
constexpr size_t WQH_OFF  = MT_OFF + 524288;          // WqhT bf16 [512][512]
constexpr size_t KN_OFF   = WQH_OFF + 131072;         // kn fp32 [1024][512]
constexpr size_t CBT_OFF  = KN_OFF + 524288;          // cbt bf16 [512][1024]
constexpr size_t NSQ_OFF  = CBT_OFF + 262144;         // normsq fp32 [65536]
constexpr size_t AVG_OFF  = NSQ_OFF + 65536;
constexpr size_t CNT_OFF  = AVG_OFF + 1024;
constexpr size_t SCAL_OFF = CNT_OFF + 1024;           // [0]=ent_sum, [1]=vq_sum

typedef __attribute__((ext_vector_type(8))) short short8;
typedef __attribute__((ext_vector_type(4))) float f32x4;
typedef _Float16 h4 __attribute__((ext_vector_type(4)));

__device__ __forceinline__ unsigned short f2bf(float f) {
  unsigned int u = __float_as_uint(f);
  unsigned int r = (u + 0x7fffu + ((u >> 16) & 1u)) >> 16;
  return (unsigned short)r;
}

// async global->LDS, 16B/lane. LDS dest must be wave-uniform base (HW adds lane*16).
__device__ __forceinline__ void gl_lds16(const void* g, void* l) {
  __builtin_amdgcn_global_load_lds(
      (const __attribute__((address_space(1))) unsigned int*)g,
      (__attribute__((address_space(3))) unsigned int*)l, 16, 0, 0);
}

__global__ __launch_bounds__(256) void init_kernel(float* small, float* nsq) {
  int i = blockIdx.x * 256 + threadIdx.x;
  if (i < 2050) small[i] = 0.f;     // avg_probs + counts + 2 scalars
  if (i < NT_) nsq[i] = 0.f;
}

// kn = l2norm(codebook @ Wk), row-major [1024][512] (NO 1/sqrt(A) fold)
__global__ __launch_bounds__(256) void knorm_kernel(const float* __restrict__ cb,
                                                    const float* __restrict__ Wk,
                                                    float* __restrict__ kn) {
  __shared__ float cb_s[4][A_];
  __shared__ float norm_s[4];
  int tid = threadIdx.x;
  int r0 = blockIdx.x * 4;
  for (int i = tid; i < 4 * A_; i += 256) {
    int r = i >> 9, c = i & 511;
    cb_s[r][c] = cb[(size_t)(r0 + r) * C_ + c];
  }
  if (tid < 4) norm_s[tid] = 0.f;
  __syncthreads();
  float acc[4][2] = {};
  for (int c = 0; c < C_; ++c) {
    float w0 = Wk[(size_t)c * A_ + tid];
    float w1 = Wk[(size_t)c * A_ + tid + 256];
#pragma unroll
    for (int r = 0; r < 4; ++r) {
      float xv = cb_s[r][c];
      acc[r][0] += xv * w0;
      acc[r][1] += xv * w1;
    }
  }
#pragma unroll
  for (int r = 0; r < 4; ++r) {
    float ss = acc[r][0] * acc[r][0] + acc[r][1] * acc[r][1];
#pragma unroll
    for (int off = 32; off > 0; off >>= 1) ss += __shfl_down(ss, off, 64);
    if ((tid & 63) == 0) atomicAdd(&norm_s[r], ss);
  }
  __syncthreads();
#pragma unroll
  for (int r = 0; r < 4; ++r) {
    float scale = 1.0f / (sqrtf(norm_s[r]) + 1e-8f);
    kn[(size_t)(r0 + r) * A_ + tid] = acc[r][0] * scale;
    kn[(size_t)(r0 + r) * A_ + tid + 256] = acc[r][1] * scale;
  }
}

// M = Wq @ kn^T  (fp64 accumulate), outputs MhT bf16 [j][c] and MT fp32 [j][c]
__global__ __launch_bounds__(256) void m_kernel(const float* __restrict__ Wq,
                                                const float* __restrict__ kn,
                                                unsigned short* __restrict__ MhT,
                                                float* __restrict__ MT) {
  __shared__ float kn_s[4][512];
  int tid = threadIdx.x;
  int j0 = blockIdx.x * 4;
  for (int i = tid; i < 4 * 512; i += 256) {
    int jj = i >> 9, a = i & 511;
    kn_s[jj][a] = kn[(size_t)(j0 + jj) * 512 + a];
  }
  __syncthreads();
  double acc[2][4] = {};
  for (int a0 = 0; a0 < 512; a0 += 4) {
    float4 w0 = *(const float4*)&Wq[(size_t)tid * 512 + a0];
    float4 w1 = *(const float4*)&Wq[(size_t)(tid + 256) * 512 + a0];
#pragma unroll
    for (int jj = 0; jj < 4; ++jj) {
      float4 kv = *(float4*)&kn_s[jj][a0];
      acc[0][jj] += (double)w0.x * kv.x + (double)w0.y * kv.y +
                    (double)w0.z * kv.z + (double)w0.w * kv.w;
      acc[1][jj] += (double)w1.x * kv.x + (double)w1.y * kv.y +
                    (double)w1.z * kv.z + (double)w1.w * kv.w;
    }
  }
#pragma unroll
  for (int jj = 0; jj < 4; ++jj) {
    int j = j0 + jj;
    float m0 = (float)acc[0][jj], m1 = (float)acc[1][jj];
    MhT[(size_t)j * 512 + tid] = f2bf(m0);
    MhT[(size_t)j * 512 + tid + 256] = f2bf(m1);
    MT[(size_t)j * 512 + tid] = m0;
    MT[(size_t)j * 512 + tid + 256] = m1;
  }
}

// WqhT[j][c] = bf16(Wq[c][j])
__global__ __launch_bounds__(256) void wqht_kernel(const float* __restrict__ Wq,
                                                   unsigned short* __restrict__ WqhT) {
  int idx = blockIdx.x * 256 + threadIdx.x;   // 262144
  int j = idx >> 9, c = idx & 511;
  WqhT[idx] = f2bf(Wq[(size_t)c * 512 + j]);
}

// cbT[c][k] = bf16(cb[k][c]) — B operand for the z_q MFMA
__global__ __launch_bounds__(256) void cbt_kernel(const float* __restrict__ cb,
                                                  unsigned short* __restrict__ cbt) {
  int idx = blockIdx.x * 256 + threadIdx.x;   // 524288 total
  int c = idx >> 10, k = idx & 1023;
  cbt[(size_t)c * K_ + k] = f2bf(cb[(size_t)k * C_ + c]);
}

// xhT[row][c] = bf16(x[n][c][t]),  row = n*1024 + t  (LDS transpose)
__global__ __launch_bounds__(256) void xsplit_kernel(const float* __restrict__ x,
                                                     unsigned short* __restrict__ xhT) {
  __shared__ float tile[64][65];
  int tid = threadIdx.x;
  int n = blockIdx.x >> 4;
  int t0 = (blockIdx.x & 15) * 64;
  for (int c0 = 0; c0 < 512; c0 += 64) {
    __syncthreads();
    {
      int t = tid & 63, cg = tid >> 6;
#pragma unroll
      for (int cl = 0; cl < 16; ++cl) {
        int cc = cl * 4 + cg;
        tile[cc][t] = x[(((size_t)(n * 512 + c0 + cc)) << 10) + t0 + t];
      }
    }
    __syncthreads();
    {
      int c = tid & 63, tg = tid >> 6;
#pragma unroll
      for (int tl = 0; tl < 16; ++tl) {
        int tt = tl * 4 + tg;
        xhT[(((size_t)(n * 1024 + t0 + tt)) << 9) + c0 + c] = f2bf(tile[c][tt]);
      }
    }
  }
}

// d_kernel v4: m97-structure GEMM, grid (512,2) x 6 in-kernel y-iterations.
// __launch_bounds__(256,3): occupancy was reg-limited to 2 waves/SIMD
// (112 VGPR + 64 AGPR acc = 176 > 512/3); forcing 3 waves/EU squeezes VGPR
// to <=106 -> 3 blocks/CU resident (grid 1024 provides them), hiding the
// per-K-step vmcnt-drain barrier. Math identical to v3.
__global__ __launch_bounds__(256, 3) void d_kernel(const unsigned short* __restrict__ xhT,
                                                   const unsigned short* __restrict__ MhT,
                                                   const unsigned short* __restrict__ WqhT,
                                                   _Float16* __restrict__ D16,
                                                   float* __restrict__ nsq) {
  __shared__ __align__(16) unsigned char As[16384];   // [128 rows][128 B] swizzled
  __shared__ __align__(16) unsigned char Bs[16384];
  int tid = threadIdx.x;
  int wv = tid >> 6, lane = tid & 63;
  int wr = wv >> 1, wc = wv & 1;
  int r0 = blockIdx.x * 128;
  const char* Abyte = (const char*)xhT;

  // staging geometry (k0-independent): per round r, this lane fills LDS phys
  // offset d = r*4096 + wv*1024 + lane*16 -> tile row = d>>7, byte-in-row
  // kb = d&127; the logical k-byte stored there is kb ^ ((row&7)<<4).
  int srow[4], skb[4];
#pragma unroll
  for (int r = 0; r < 4; ++r) {
    int d = r * 4096 + wv * 1024 + lane * 16;
    srow[r] = d >> 7;
    skb[r] = (d & 127) ^ ((srow[r] & 7) << 4);
  }

  // fragment geometry: lane ll reads row rt*16+ll (within wave's 64-row strip),
  // k elements lh..lh+7
  int ll = lane & 15, lh2 = ((lane >> 4) * 8) * 2;   // byte offset of k-group
  int arowb[4], axm[4], browb[4], bxm[4];
#pragma unroll
  for (int t = 0; t < 4; ++t) {
    int ar = wr * 64 + t * 16 + ll;
    arowb[t] = ar * 128; axm[t] = (ar & 7) << 4;
    int br = wc * 64 + t * 16 + ll;
    browb[t] = br * 128; bxm[t] = (br & 7) << 4;
  }

  for (int yy = 0; yy < 6; ++yy) {
    int y = blockIdx.y * 6 + yy;
    bool isq = (y >= 8);
    const char* Bbyte = (const char*)(isq ? (WqhT + ((size_t)(y - 8) * 128) * 512)
                                          : (MhT + ((size_t)y * 128) * 512));

    f32x4 acc[4][4] = {};
    for (int k0 = 0; k0 < 512; k0 += 64) {
      __syncthreads();   // previous K-step's (or prev y's last) reads done before overwrite
#pragma unroll
      for (int r = 0; r < 4; ++r)
        gl_lds16(Abyte + (size_t)(r0 + srow[r]) * 1024 + (size_t)k0 * 2 + skb[r],
                 As + r * 4096 + wv * 1024);
#pragma unroll
      for (int r = 0; r < 4; ++r)
        gl_lds16(Bbyte + (size_t)srow[r] * 1024 + (size_t)k0 * 2 + skb[r],
                 Bs + r * 4096 + wv * 1024);
      __syncthreads();   // compiler drains vmcnt before barrier -> data landed
#pragma unroll
      for (int kk = 0; kk < 2; ++kk) {
        int kb = kk * 64 + lh2;        // logical k-byte of this lane's group
        short8 af[4], bf[4];
#pragma unroll
        for (int rt = 0; rt < 4; ++rt)
          af[rt] = *(const short8*)(As + arowb[rt] + (kb ^ axm[rt]));
#pragma unroll
        for (int ct = 0; ct < 4; ++ct)
          bf[ct] = *(const short8*)(Bs + browb[ct] + (kb ^ bxm[ct]));
#pragma unroll
        for (int rt = 0; rt < 4; ++rt)
#pragma unroll
          for (int ct = 0; ct < 4; ++ct)
            acc[rt][ct] = __builtin_amdgcn_mfma_f32_16x16x32_bf16(af[rt], bf[ct], acc[rt][ct], 0, 0, 0);
      }
    }

    // C/D layout: col = ct*16 + ll, row = rt*16 + (lane>>4)*4 + reg (per 64x64)
    if (!isq) {
      int cbase = y * 128 + wc * 64;
#pragma unroll
      for (int rt = 0; rt < 4; ++rt)
#pragma unroll
        for (int ct = 0; ct < 4; ++ct) {
          int col = cbase + ct * 16 + ll;
#pragma unroll
          for (int reg = 0; reg < 4; ++reg) {
            int row = r0 + wr * 64 + rt * 16 + (lane >> 4) * 4 + reg;
            D16[(size_t)row * 1024 + col] = (_Float16)acc[rt][ct][reg];
          }
        }
    } else {
#pragma unroll
      for (int rt = 0; rt < 4; ++rt)
#pragma unroll
        for (int reg = 0; reg < 4; ++reg) {
          float sq = 0.f;
#pragma unroll
          for (int ct = 0; ct < 4; ++ct) { float v = acc[rt][ct][reg]; sq += v * v; }
          sq += __shfl_xor(sq, 1, 64);
          sq += __shfl_xor(sq, 2, 64);
          sq += __shfl_xor(sq, 4, 64);
          sq += __shfl_xor(sq, 8, 64);
          if (ll == 0)
            atomicAdd(&nsq[r0 + wr * 64 + rt * 16 + (lane >> 4) * 4 + reg], sq);
        }
    }
  }
}

// Stats v4: identical candidate logic to v3, but rechecks are DEFERRED to a
// per-wave epilogue. A wave's 8 rows are 8 consecutive t of one n -> their
// x-gathers touch the SAME 512 cache lines; running them back-to-back (no
// intervening D16/att streams) keeps the lines L1/L2-hot, cutting the
// ~32KB/row HBM over-fetch to ~once per wave.
__global__ __launch_bounds__(256) void stats_kernel(
    const float* __restrict__ x, const _Float16* __restrict__ D16,
    const float* __restrict__ nsq, const float* __restrict__ MT,
    unsigned short* __restrict__ att, float* __restrict__ out,
    float* __restrict__ avg_probs, float* __restrict__ counts,
    float* __restrict__ scal) {
  __shared__ float avg_s[K_];
  __shared__ float red_s;
  __shared__ short cand_s[4][8][16];
  __shared__ int cnt_s[4][8];
  int tid = threadIdx.x;
  int wv = tid >> 6, lane = tid & 63;
  int r0 = blockIdx.x * 32;
  for (int i = tid; i < K_; i += 256) avg_s[i] = 0.f;
  if (tid == 0) red_s = 0.f;
  __syncthreads();

  float entp = 0.f;
  float p_loc[16] = {};
  unsigned defer = 0u;   // wave-uniform bitmask of deferred rows
  for (int i = 0; i < 8; ++i) {
    int row = r0 + wv * 8 + i;
    float s = 1.0f / ((sqrtf(nsq[row]) + 1e-8f) * 22.62741699796952f);
    // load logits (16 per lane: kk = lane*4 + kl + 256*kj)
    float l[16];
#pragma unroll
    for (int kj = 0; kj < 4; ++kj) {
      h4 v = *(const h4*)&D16[(size_t)row * 1024 + lane * 4 + kj * 256];
#pragma unroll
      for (int u = 0; u < 4; ++u) l[kj * 4 + u] = (float)v[u] * s;
    }
    // single value-only wave max
    float m0 = l[0];
#pragma unroll
    for (int k = 1; k < 16; ++k) m0 = fmaxf(m0, l[k]);
#pragma unroll
    for (int off = 1; off < 64; off <<= 1) m0 = fmaxf(m0, __shfl_xor(m0, off, 64));
    // candidate mask within the value window
    float thr = m0 - 3.0e-4f;
    unsigned cmask = 0u;
#pragma unroll
    for (int k = 0; k < 16; ++k) cmask |= (l[k] >= thr) ? (1u << k) : 0u;
    int pc = __popc(cmask);
    unsigned long long b1 = __ballot(pc != 0);
    unsigned long long b2 = __ballot(pc > 1);
    if (b2 == 0ull && __popcll(b1) == 1) {
      // unique candidate wave-wide == argmax (window >> approx error bound)
      int b = __ffs(cmask) - 1;                       // valid on owner lane
      int kk = lane * 4 + (b & 3) + 256 * (b >> 2);
      int bi = __shfl(kk, (int)(__ffsll(b1) - 1), 64);
      if (lane == 0) {
        out[CODE_OFF + row] = (float)bi;
        atomicAdd(&counts[bi], 1.0f);
      }
    } else {
      // record candidates; exact recheck deferred to wave epilogue
      if (lane == 0) cnt_s[wv][i] = 0;
      int base = 0;
      if (pc) base = atomicAdd(&cnt_s[wv][i], pc);    // same-wave LDS: in-order
      unsigned mrem = cmask;
      for (int t2 = 0; t2 < pc; ++t2) {
        int b = __ffs(mrem) - 1;
        mrem &= mrem - 1;
        int slot = base + t2;
        if (slot < 16)
          cand_s[wv][i][slot] = (short)(lane * 4 + (b & 3) + 256 * (b >> 2));
      }
      defer |= 1u << i;
    }
    // softmax stats (shift by m0), exps computed once and cached
    float E1[16], E100[16];
    float S1 = 0.f, S100 = 0.f, U100 = 0.f;
#pragma unroll
    for (int k = 0; k < 16; ++k) {
      float e = l[k] - m0;
      float v1 = __expf(e);
      E1[k] = v1;
      S1 += v1;
      float e100 = e * 100.0f;
      float v100 = __expf(e100);
      E100[k] = v100;
      S100 += v100;
      U100 += v100 * e100;
    }
#pragma unroll
    for (int off = 1; off < 64; off <<= 1) {
      S1 += __shfl_xor(S1, off, 64);
      S100 += __shfl_xor(S100, off, 64);
      U100 += __shfl_xor(U100, off, 64);
    }
    float invS1 = 1.0f / S1;
    float invS100 = 1.0f / S100;
    if (lane == 0) entp += __logf(S100) - U100 * invS100;
#pragma unroll
    for (int kj = 0; kj < 4; ++kj) {
      ushort4 pk;
      pk.x = f2bf(E1[kj * 4 + 0] * invS1);
      pk.y = f2bf(E1[kj * 4 + 1] * invS1);
      pk.z = f2bf(E1[kj * 4 + 2] * invS1);
      pk.w = f2bf(E1[kj * 4 + 3] * invS1);
      *(ushort4*)&att[(size_t)row * K_ + lane * 4 + kj * 256] = pk;
      p_loc[kj * 4 + 0] += E100[kj * 4 + 0] * invS100;
      p_loc[kj * 4 + 1] += E100[kj * 4 + 1] * invS100;
      p_loc[kj * 4 + 2] += E100[kj * 4 + 2] * invS100;
      p_loc[kj * 4 + 3] += E100[kj * 4 + 3] * invS100;
    }
  }
  // deferred exact rechecks, back-to-back for x-line reuse
  int nrow = r0 >> 10;   // block spans one n
  while (defer) {
    int i = __ffs(defer) - 1;
    defer &= defer - 1;
    int row = r0 + wv * 8 + i;
    int trow = row & 1023;
    float xr[8];
#pragma unroll
    for (int u = 0; u < 8; ++u)
      xr[u] = x[(((size_t)(nrow * 512 + lane + u * 64)) << 10) + trow];
    int cnt = cnt_s[wv][i];
    if (cnt > 16) cnt = 16;
    float best = -1e30f;
    int bi = K_;
    for (int it = 0; it < cnt; ++it) {
      int j = cand_s[wv][i][it];
      const float* mrow = &MT[((size_t)j) << 9];
      float sd = 0.f;
#pragma unroll
      for (int u = 0; u < 8; ++u) sd = fmaf(xr[u], mrow[lane + u * 64], sd);
#pragma unroll
      for (int off = 1; off < 64; off <<= 1) sd += __shfl_xor(sd, off, 64);
      if (sd > best || (sd == best && j < bi)) { best = sd; bi = j; }
    }
    if (lane == 0) {
      out[CODE_OFF + row] = (float)bi;
      atomicAdd(&counts[bi], 1.0f);
    }
  }
#pragma unroll
  for (int kj = 0; kj < 4; ++kj)
#pragma unroll
    for (int kl = 0; kl < 4; ++kl)
      atomicAdd(&avg_s[lane * 4 + kl + 256 * kj], p_loc[kj * 4 + kl]);
  if (lane == 0) atomicAdd(&red_s, entp);
  __syncthreads();
  if (tid == 0) atomicAdd(&scal[0], red_s);
  for (int i = tid; i < K_; i += 256) atomicAdd(&avg_probs[i], avg_s[i]);
}

// zq v3: m97-structure GEMM + __launch_bounds__(256,3) (same reg-pressure
// argument as d_kernel: 112 VGPR + 64 AGPR capped occupancy at 2 waves/SIMD).
__global__ __launch_bounds__(256, 3) void zq_kernel(const float* __restrict__ x,
                                                    const unsigned short* __restrict__ att,
                                                    const unsigned short* __restrict__ cbt,
                                                    float* __restrict__ out,
                                                    float* __restrict__ scal) {
  __shared__ __align__(16) unsigned char As[16384];   // [128 rows][128 B] swizzled
  __shared__ __align__(16) unsigned char Bs[16384];
  int tid = threadIdx.x;
  int wv = tid >> 6, lane = tid & 63;
  int wr = wv >> 1, wc = wv & 1;
  int r0 = blockIdx.x * 128;
  int y = blockIdx.y;                                 // col tile: channels y*128..
  const char* Abyte = (const char*)(att + (size_t)r0 * K_);
  const char* Bbyte = (const char*)(cbt + (size_t)(y * 128) * K_);

  int srow[4], skb[4];
#pragma unroll
  for (int r = 0; r < 4; ++r) {
    int d = r * 4096 + wv * 1024 + lane * 16;
    srow[r] = d >> 7;
    skb[r] = (d & 127) ^ ((srow[r] & 7) << 4);
  }

  int ll = lane & 15, lh2 = ((lane >> 4) * 8) * 2;
  int arowb[4], axm[4], browb[4], bxm[4];
#pragma unroll
  for (int t = 0; t < 4; ++t) {
    int ar = wr * 64 + t * 16 + ll;
    arowb[t] = ar * 128; axm[t] = (ar & 7) << 4;
    int br = wc * 64 + t * 16 + ll;
    browb[t] = br * 128; bxm[t] = (br & 7) << 4;
  }

  f32x4 acc[4][4] = {};
  for (int k0 = 0; k0 < 1024; k0 += 64) {
    __syncthreads();
#pragma unroll
    for (int r = 0; r < 4; ++r)
      gl_lds16(Abyte + (size_t)srow[r] * 2048 + (size_t)k0 * 2 + skb[r],
               As + r * 4096 + wv * 1024);
#pragma unroll
    for (int r = 0; r < 4; ++r)
      gl_lds16(Bbyte + (size_t)srow[r] * 2048 + (size_t)k0 * 2 + skb[r],
               Bs + r * 4096 + wv * 1024);
    __syncthreads();
#pragma unroll
    for (int kk = 0; kk < 2; ++kk) {
      int kb = kk * 64 + lh2;
      short8 af[4], bf[4];
#pragma unroll
      for (int rt = 0; rt < 4; ++rt)
        af[rt] = *(const short8*)(As + arowb[rt] + (kb ^ axm[rt]));
#pragma unroll
      for (int ct = 0; ct < 4; ++ct)
        bf[ct] = *(const short8*)(Bs + browb[ct] + (kb ^ bxm[ct]));
#pragma unroll
      for (int rt = 0; rt < 4; ++rt)
#pragma unroll
        for (int ct = 0; ct < 4; ++ct)
          acc[rt][ct] = __builtin_amdgcn_mfma_f32_16x16x32_bf16(af[rt], bf[ct], acc[rt][ct], 0, 0, 0);
    }
  }

  // epilogue: row = r0 + wr*64 + rt*16 + (lane>>4)*4 + reg; col c = y*128 + wc*64 + ct*16 + ll
  int nb = r0 >> 10, t0 = (r0 & 1023) + wr * 64;
  float vqp = 0.f;
#pragma unroll
  for (int rt = 0; rt < 4; ++rt) {
    int t = t0 + rt * 16 + (lane >> 4) * 4;
#pragma unroll
    for (int ct = 0; ct < 4; ++ct) {
      int c = y * 128 + wc * 64 + ct * 16 + ll;
      size_t xi = (size_t)nb * C_ * T_ + (size_t)c * T_ + t;
      float4 xv = *(const float4*)&x[xi];
      float4 z = make_float4(acc[rt][ct][0], acc[rt][ct][1], acc[rt][ct][2], acc[rt][ct][3]);
      float d0 = z.x - xv.x, d1 = z.y - xv.y, d2 = z.z - xv.z, d3 = z.w - xv.w;
      vqp += d0 * d0 + d1 * d1 + d2 * d2 + d3 * d3;
      *(float4*)&out[XD_OFF + xi] = z;
    }
  }
#pragma unroll
  for (int off = 1; off < 64; off <<= 1) vqp += __shfl_xor(vqp, off, 64);
  if (lane == 0) atomicAdd(&scal[1], vqp);
}

__global__ __launch_bounds__(1024) void finalize_kernel(const float* __restrict__ avgp,
                                                        const float* __restrict__ counts,
                                                        const float* __restrict__ scal,
                                                        float* __restrict__ out) {
  __shared__ float r1[16], r2[16];
  int tid = threadIdx.x;
  float a = avgp[tid] * (1.0f / 65536.0f);
  float t1 = a * logf(a + 1e-5f);
  float p = counts[tid] * (1.0f / 65536.0f);
  float t2 = p * logf(p + 1e-7f);
#pragma unroll
  for (int off = 1; off < 64; off <<= 1) {
    t1 += __shfl_xor(t1, off, 64);
    t2 += __shfl_xor(t2, off, 64);
  }
  int wv = tid >> 6, lane = tid & 63;
  if (lane == 0) { r1[wv] = t1; r2[wv] = t2; }
  __syncthreads();
  if (tid == 0) {
    float T1 = 0.f, T2 = 0.f;
    for (int i = 0; i < 16; ++i) { T1 += r1[i]; T2 += r2[i]; }
    float sample_entropy = scal[0] * (1.0f / 65536.0f);
    float avg_entropy = -T1;
    out[SC_OFF + 0] = sample_entropy;
    out[SC_OFF + 1] = avg_entropy;
    out[SC_OFF + 2] = sample_entropy - avg_entropy;
    out[SC_OFF + 3] = expf(-T2);
    out[SC_OFF + 4] = scal[1] * (1.0f / 33554432.0f);
  }
}

extern "C" void kernel_launch(void* const* d_in, const int* in_sizes, int n_in,
                              void* d_out, int out_size, void* d_ws, size_t ws_size,
                              hipStream_t stream) {
  const float* x  = (const float*)d_in[0];
  const float* cb = (const float*)d_in[1];
  const float* Wq = (const float*)d_in[2];
  const float* Wk = (const float*)d_in[3];
  float* out = (float*)d_out;
  float* ws = (float*)d_ws;

  unsigned short* xhT = (unsigned short*)ws;            // bf16 [NT][512]
  unsigned short* att = (unsigned short*)ws;            // bf16 [NT][1024] (alias, post-d_kernel)
  unsigned short* MhT = (unsigned short*)(ws + MHT_OFF);
  float* MT           = ws + MT_OFF;
  unsigned short* WqhT = (unsigned short*)(ws + WQH_OFF);
  float* kn           = ws + KN_OFF;
  unsigned short* cbt = (unsigned short*)(ws + CBT_OFF);
  float* nsq          = ws + NSQ_OFF;
  float* avgp         = ws + AVG_OFF;
  float* counts       = ws + CNT_OFF;
  float* scal         = ws + SCAL_OFF;
  _Float16* D16       = (_Float16*)d_out;               // fp16 [NT][1024] == XD region

  init_kernel<<<256, 256, 0, stream>>>(avgp, nsq);
  knorm_kernel<<<K_ / 4, 256, 0, stream>>>(cb, Wk, kn);
  m_kernel<<<K_ / 4, 256, 0, stream>>>(Wq, kn, MhT, MT);
  wqht_kernel<<<1024, 256, 0, stream>>>(Wq, WqhT);
  cbt_kernel<<<(C_ * K_) / 256, 256, 0, stream>>>(cb, cbt);
  xsplit_kernel<<<1024, 256, 0, stream>>>(x, xhT);
  d_kernel<<<dim3(NT_ / 128, 2), 256, 0, stream>>>(xhT, MhT, WqhT, D16, nsq);
  stats_kernel<<<NT_ / 32, 256, 0, stream>>>(x, D16, nsq, MT, att, out, avgp, counts, scal);
  zq_kernel<<<dim3(NT_ / 128, 4), 256, 0, stream>>>(x, att, cbt, out, scal);
  finalize_kernel<<<1, 1024, 0, stream>>>(avgp, counts, scal, out);
}

// Round 9
// 845.727 us; speedup vs baseline: 1.1149x; 1.1149x over previous
//
#include <hip/hip_runtime.h>
#include <hip/hip_bf16.h>

// Problem dims (fixed by reference)
constexpr int N_ = 64, C_ = 512, T_ = 1024;
constexpr int NT_ = N_ * T_;        // 65536 rows
constexpr int K_ = 1024;            // nb_code
constexpr int A_ = 512;             // attn_dim

// Output layout (floats, concatenated in return order)
constexpr size_t XD_OFF   = 0;                       // 33554432 floats
constexpr size_t SC_OFF   = (size_t)N_ * C_ * T_;    // 5 scalars
constexpr size_t CODE_OFF = SC_OFF + 5;              // 65536 code_idx as float
// NOTE: D~ (fp16 [NT][1024] = 134217728 B) EXACTLY fits the XD region of d_out.
// It is written by d_kernel, consumed by stats_kernel, then zq_kernel
// overwrites the region with x_d (stream-ordered, same launch).

// Workspace layout (floats)
// region0 (128 MB): xhT bf16 [NT][512] (first 64 MB); att bf16 [NT][1024]
//   aliases the same base — xhT is dead once stats_kernel (which writes att)
//   runs, and d_kernel (the only xhT reader) fully precedes it.
constexpr size_t MHT_OFF  = 33554432;                 // MhT bf16 [1024][512]
constexpr size_t MT_OFF   = MHT_OFF + 262144;         // MT fp32 [1024][512]
constexpr size_t WQH_OFF  = MT_OFF + 524288;          // WqhT bf16 [512][512]
constexpr size_t KN_OFF   = WQH_OFF + 131072;         // kn fp32 [1024][512]
constexpr size_t CBT_OFF  = KN_OFF + 524288;          // cbt bf16 [512][1024]
constexpr size_t NSQ_OFF  = CBT_OFF + 262144;         // normsq fp32 [65536]
constexpr size_t AVG_OFF  = NSQ_OFF + 65536;
constexpr size_t CNT_OFF  = AVG_OFF + 1024;
constexpr size_t SCAL_OFF = CNT_OFF + 1024;           // [0]=ent_sum, [1]=vq_sum

typedef __attribute__((ext_vector_type(8))) short short8;
typedef __attribute__((ext_vector_type(4))) float f32x4;
typedef _Float16 h4 __attribute__((ext_vector_type(4)));

__device__ __forceinline__ unsigned short f2bf(float f) {
  unsigned int u = __float_as_uint(f);
  unsigned int r = (u + 0x7fffu + ((u >> 16) & 1u)) >> 16;
  return (unsigned short)r;
}

// async global->LDS, 16B/lane. LDS dest must be wave-uniform base (HW adds lane*16).
__device__ __forceinline__ void gl_lds16(const void* g, void* l) {
  __builtin_amdgcn_global_load_lds(
      (const __attribute__((address_space(1))) unsigned int*)g,
      (__attribute__((address_space(3))) unsigned int*)l, 16, 0, 0);
}

__global__ __launch_bounds__(256) void init_kernel(float* small, float* nsq) {
  int i = blockIdx.x * 256 + threadIdx.x;
  if (i < 2050) small[i] = 0.f;     // avg_probs + counts + 2 scalars
  if (i < NT_) nsq[i] = 0.f;
}

// kn = l2norm(codebook @ Wk), row-major [1024][512] (NO 1/sqrt(A) fold)
__global__ __launch_bounds__(256) void knorm_kernel(const float* __restrict__ cb,
                                                    const float* __restrict__ Wk,
                                                    float* __restrict__ kn) {
  __shared__ float cb_s[4][A_];
  __shared__ float norm_s[4];
  int tid = threadIdx.x;
  int r0 = blockIdx.x * 4;
  for (int i = tid; i < 4 * A_; i += 256) {
    int r = i >> 9, c = i & 511;
    cb_s[r][c] = cb[(size_t)(r0 + r) * C_ + c];
  }
  if (tid < 4) norm_s[tid] = 0.f;
  __syncthreads();
  float acc[4][2] = {};
  for (int c = 0; c < C_; ++c) {
    float w0 = Wk[(size_t)c * A_ + tid];
    float w1 = Wk[(size_t)c * A_ + tid + 256];
#pragma unroll
    for (int r = 0; r < 4; ++r) {
      float xv = cb_s[r][c];
      acc[r][0] += xv * w0;
      acc[r][1] += xv * w1;
    }
  }
#pragma unroll
  for (int r = 0; r < 4; ++r) {
    float ss = acc[r][0] * acc[r][0] + acc[r][1] * acc[r][1];
#pragma unroll
    for (int off = 32; off > 0; off >>= 1) ss += __shfl_down(ss, off, 64);
    if ((tid & 63) == 0) atomicAdd(&norm_s[r], ss);
  }
  __syncthreads();
#pragma unroll
  for (int r = 0; r < 4; ++r) {
    float scale = 1.0f / (sqrtf(norm_s[r]) + 1e-8f);
    kn[(size_t)(r0 + r) * A_ + tid] = acc[r][0] * scale;
    kn[(size_t)(r0 + r) * A_ + tid + 256] = acc[r][1] * scale;
  }
}

// M = Wq @ kn^T  (fp64 accumulate), outputs MhT bf16 [j][c] and MT fp32 [j][c]
__global__ __launch_bounds__(256) void m_kernel(const float* __restrict__ Wq,
                                                const float* __restrict__ kn,
                                                unsigned short* __restrict__ MhT,
                                                float* __restrict__ MT) {
  __shared__ float kn_s[4][512];
  int tid = threadIdx.x;
  int j0 = blockIdx.x * 4;
  for (int i = tid; i < 4 * 512; i += 256) {
    int jj = i >> 9, a = i & 511;
    kn_s[jj][a] = kn[(size_t)(j0 + jj) * 512 + a];
  }
  __syncthreads();
  double acc[2][4] = {};
  for (int a0 = 0; a0 < 512; a0 += 4) {
    float4 w0 = *(const float4*)&Wq[(size_t)tid * 512 + a0];
    float4 w1 = *(const float4*)&Wq[(size_t)(tid + 256) * 512 + a0];
#pragma unroll
    for (int jj = 0; jj < 4; ++jj) {
      float4 kv = *(float4*)&kn_s[jj][a0];
      acc[0][jj] += (double)w0.x * kv.x + (double)w0.y * kv.y +
                    (double)w0.z * kv.z + (double)w0.w * kv.w;
      acc[1][jj] += (double)w1.x * kv.x + (double)w1.y * kv.y +
                    (double)w1.z * kv.z + (double)w1.w * kv.w;
    }
  }
#pragma unroll
  for (int jj = 0; jj < 4; ++jj) {
    int j = j0 + jj;
    float m0 = (float)acc[0][jj], m1 = (float)acc[1][jj];
    MhT[(size_t)j * 512 + tid] = f2bf(m0);
    MhT[(size_t)j * 512 + tid + 256] = f2bf(m1);
    MT[(size_t)j * 512 + tid] = m0;
    MT[(size_t)j * 512 + tid + 256] = m1;
  }
}

// WqhT[j][c] = bf16(Wq[c][j])
__global__ __launch_bounds__(256) void wqht_kernel(const float* __restrict__ Wq,
                                                   unsigned short* __restrict__ WqhT) {
  int idx = blockIdx.x * 256 + threadIdx.x;   // 262144
  int j = idx >> 9, c = idx & 511;
  WqhT[idx] = f2bf(Wq[(size_t)c * 512 + j]);
}

// cbT[c][k] = bf16(cb[k][c]) — B operand for the z_q MFMA
__global__ __launch_bounds__(256) void cbt_kernel(const float* __restrict__ cb,
                                                  unsigned short* __restrict__ cbt) {
  int idx = blockIdx.x * 256 + threadIdx.x;   // 524288 total
  int c = idx >> 10, k = idx & 1023;
  cbt[(size_t)c * K_ + k] = f2bf(cb[(size_t)k * C_ + c]);
}

// xhT[row][c] = bf16(x[n][c][t]),  row = n*1024 + t  (LDS transpose)
__global__ __launch_bounds__(256) void xsplit_kernel(const float* __restrict__ x,
                                                     unsigned short* __restrict__ xhT) {
  __shared__ float tile[64][65];
  int tid = threadIdx.x;
  int n = blockIdx.x >> 4;
  int t0 = (blockIdx.x & 15) * 64;
  for (int c0 = 0; c0 < 512; c0 += 64) {
    __syncthreads();
    {
      int t = tid & 63, cg = tid >> 6;
#pragma unroll
      for (int cl = 0; cl < 16; ++cl) {
        int cc = cl * 4 + cg;
        tile[cc][t] = x[(((size_t)(n * 512 + c0 + cc)) << 10) + t0 + t];
      }
    }
    __syncthreads();
    {
      int c = tid & 63, tg = tid >> 6;
#pragma unroll
      for (int tl = 0; tl < 16; ++tl) {
        int tt = tl * 4 + tg;
        xhT[(((size_t)(n * 1024 + t0 + tt)) << 9) + c0 + c] = f2bf(tile[c][tt]);
      }
    }
  }
}

// d_kernel v5: m97-structure GEMM (round-6 body, launch_bounds reverted) with
// XCD-aware block mapping (T1). Round-robin bid->XCD (bid&7); each XCD's
// local sequence i=bid>>3 enumerates its 64 A-panels with the panel's 12
// y-tiles BACK-TO-BACK -> ~5 concurrent panels x 131 KB = 0.7 MB per 4 MB
// XCD-L2 -> each panel fetched from HBM once (A-traffic 400->~64 MB).
// Math identical; mapping is perf-only (any XCD assignment stays correct).
__global__ __launch_bounds__(256) void d_kernel(const unsigned short* __restrict__ xhT,
                                                const unsigned short* __restrict__ MhT,
                                                const unsigned short* __restrict__ WqhT,
                                                _Float16* __restrict__ D16,
                                                float* __restrict__ nsq) {
  __shared__ __align__(16) unsigned char As[16384];   // [128 rows][128 B] swizzled
  __shared__ __align__(16) unsigned char Bs[16384];
  int tid = threadIdx.x;
  int wv = tid >> 6, lane = tid & 63;
  int wr = wv >> 1, wc = wv & 1;
  int bid = blockIdx.x;                 // 6144 = 512 panels x 12 y-tiles
  int i = bid >> 3;                     // per-XCD sequence 0..767
  int xl = i / 12, y = i - xl * 12;     // panel-local, y-tile
  int r0 = ((bid & 7) * 64 + xl) * 128; // panel rows
  bool isq = (y >= 8);
  const unsigned short* Bsrc = isq ? (WqhT + ((size_t)(y - 8) * 128) * 512)
                                   : (MhT + ((size_t)y * 128) * 512);
  const char* Abyte = (const char*)xhT;
  const char* Bbyte = (const char*)Bsrc;

  // staging geometry (k0-independent): per round r, this lane fills LDS phys
  // offset d = r*4096 + wv*1024 + lane*16 -> tile row = d>>7, byte-in-row
  // kb = d&127; the logical k-byte stored there is kb ^ ((row&7)<<4).
  int srow[4], skb[4];
#pragma unroll
  for (int r = 0; r < 4; ++r) {
    int d = r * 4096 + wv * 1024 + lane * 16;
    srow[r] = d >> 7;
    skb[r] = (d & 127) ^ ((srow[r] & 7) << 4);
  }

  // fragment geometry: lane ll reads row rt*16+ll (within wave's 64-row strip),
  // k elements lh..lh+7
  int ll = lane & 15, lh2 = ((lane >> 4) * 8) * 2;   // byte offset of k-group
  int arowb[4], axm[4], browb[4], bxm[4];
#pragma unroll
  for (int t = 0; t < 4; ++t) {
    int ar = wr * 64 + t * 16 + ll;
    arowb[t] = ar * 128; axm[t] = (ar & 7) << 4;
    int br = wc * 64 + t * 16 + ll;
    browb[t] = br * 128; bxm[t] = (br & 7) << 4;
  }

  f32x4 acc[4][4] = {};
  for (int k0 = 0; k0 < 512; k0 += 64) {
    __syncthreads();   // previous K-step's reads complete before overwrite
#pragma unroll
    for (int r = 0; r < 4; ++r)
      gl_lds16(Abyte + (size_t)(r0 + srow[r]) * 1024 + (size_t)k0 * 2 + skb[r],
               As + r * 4096 + wv * 1024);
#pragma unroll
    for (int r = 0; r < 4; ++r)
      gl_lds16(Bbyte + (size_t)srow[r] * 1024 + (size_t)k0 * 2 + skb[r],
               Bs + r * 4096 + wv * 1024);
    __syncthreads();   // compiler drains vmcnt before barrier -> data landed
#pragma unroll
    for (int kk = 0; kk < 2; ++kk) {
      int kb = kk * 64 + lh2;          // logical k-byte of this lane's group
      short8 af[4], bf[4];
#pragma unroll
      for (int rt = 0; rt < 4; ++rt)
        af[rt] = *(const short8*)(As + arowb[rt] + (kb ^ axm[rt]));
#pragma unroll
      for (int ct = 0; ct < 4; ++ct)
        bf[ct] = *(const short8*)(Bs + browb[ct] + (kb ^ bxm[ct]));
#pragma unroll
      for (int rt = 0; rt < 4; ++rt)
#pragma unroll
        for (int ct = 0; ct < 4; ++ct)
          acc[rt][ct] = __builtin_amdgcn_mfma_f32_16x16x32_bf16(af[rt], bf[ct], acc[rt][ct], 0, 0, 0);
    }
  }

  // C/D layout: col = ct*16 + ll, row = rt*16 + (lane>>4)*4 + reg (per 64x64)
  if (!isq) {
    int cbase = y * 128 + wc * 64;
#pragma unroll
    for (int rt = 0; rt < 4; ++rt)
#pragma unroll
      for (int ct = 0; ct < 4; ++ct) {
        int col = cbase + ct * 16 + ll;
#pragma unroll
        for (int reg = 0; reg < 4; ++reg) {
          int row = r0 + wr * 64 + rt * 16 + (lane >> 4) * 4 + reg;
          D16[(size_t)row * 1024 + col] = (_Float16)acc[rt][ct][reg];
        }
      }
  } else {
#pragma unroll
    for (int rt = 0; rt < 4; ++rt)
#pragma unroll
      for (int reg = 0; reg < 4; ++reg) {
        float sq = 0.f;
#pragma unroll
        for (int ct = 0; ct < 4; ++ct) { float v = acc[rt][ct][reg]; sq += v * v; }
        sq += __shfl_xor(sq, 1, 64);
        sq += __shfl_xor(sq, 2, 64);
        sq += __shfl_xor(sq, 4, 64);
        sq += __shfl_xor(sq, 8, 64);
        if (ll == 0)
          atomicAdd(&nsq[r0 + wr * 64 + rt * 16 + (lane >> 4) * 4 + reg], sq);
      }
  }
}

// Stats v4: identical candidate logic to v3, but rechecks are DEFERRED to a
// per-wave epilogue. A wave's 8 rows are 8 consecutive t of one n -> their
// x-gathers touch the SAME 512 cache lines; running them back-to-back (no
// intervening D16/att streams) keeps the lines L1/L2-hot, cutting the
// ~32KB/row HBM over-fetch to ~once per wave.
__global__ __launch_bounds__(256) void stats_kernel(
    const float* __restrict__ x, const _Float16* __restrict__ D16,
    const float* __restrict__ nsq, const float* __restrict__ MT,
    unsigned short* __restrict__ att, float* __restrict__ out,
    float* __restrict__ avg_probs, float* __restrict__ counts,
    float* __restrict__ scal) {
  __shared__ float avg_s[K_];
  __shared__ float red_s;
  __shared__ short cand_s[4][8][16];
  __shared__ int cnt_s[4][8];
  int tid = threadIdx.x;
  int wv = tid >> 6, lane = tid & 63;
  int r0 = blockIdx.x * 32;
  for (int i = tid; i < K_; i += 256) avg_s[i] = 0.f;
  if (tid == 0) red_s = 0.f;
  __syncthreads();

  float entp = 0.f;
  float p_loc[16] = {};
  unsigned defer = 0u;   // wave-uniform bitmask of deferred rows
  for (int i = 0; i < 8; ++i) {
    int row = r0 + wv * 8 + i;
    float s = 1.0f / ((sqrtf(nsq[row]) + 1e-8f) * 22.62741699796952f);
    // load logits (16 per lane: kk = lane*4 + kl + 256*kj)
    float l[16];
#pragma unroll
    for (int kj = 0; kj < 4; ++kj) {
      h4 v = *(const h4*)&D16[(size_t)row * 1024 + lane * 4 + kj * 256];
#pragma unroll
      for (int u = 0; u < 4; ++u) l[kj * 4 + u] = (float)v[u] * s;
    }
    // single value-only wave max
    float m0 = l[0];
#pragma unroll
    for (int k = 1; k < 16; ++k) m0 = fmaxf(m0, l[k]);
#pragma unroll
    for (int off = 1; off < 64; off <<= 1) m0 = fmaxf(m0, __shfl_xor(m0, off, 64));
    // candidate mask within the value window
    float thr = m0 - 3.0e-4f;
    unsigned cmask = 0u;
#pragma unroll
    for (int k = 0; k < 16; ++k) cmask |= (l[k] >= thr) ? (1u << k) : 0u;
    int pc = __popc(cmask);
    unsigned long long b1 = __ballot(pc != 0);
    unsigned long long b2 = __ballot(pc > 1);
    if (b2 == 0ull && __popcll(b1) == 1) {
      // unique candidate wave-wide == argmax (window >> approx error bound)
      int b = __ffs(cmask) - 1;                       // valid on owner lane
      int kk = lane * 4 + (b & 3) + 256 * (b >> 2);
      int bi = __shfl(kk, (int)(__ffsll(b1) - 1), 64);
      if (lane == 0) {
        out[CODE_OFF + row] = (float)bi;
        atomicAdd(&counts[bi], 1.0f);
      }
    } else {
      // record candidates; exact recheck deferred to wave epilogue
      if (lane == 0) cnt_s[wv][i] = 0;
      int base = 0;
      if (pc) base = atomicAdd(&cnt_s[wv][i], pc);    // same-wave LDS: in-order
      unsigned mrem = cmask;
      for (int t2 = 0; t2 < pc; ++t2) {
        int b = __ffs(mrem) - 1;
        mrem &= mrem - 1;
        int slot = base + t2;
        if (slot < 16)
          cand_s[wv][i][slot] = (short)(lane * 4 + (b & 3) + 256 * (b >> 2));
      }
      defer |= 1u << i;
    }
    // softmax stats (shift by m0), exps computed once and cached
    float E1[16], E100[16];
    float S1 = 0.f, S100 = 0.f, U100 = 0.f;
#pragma unroll
    for (int k = 0; k < 16; ++k) {
      float e = l[k] - m0;
      float v1 = __expf(e);
      E1[k] = v1;
      S1 += v1;
      float e100 = e * 100.0f;
      float v100 = __expf(e100);
      E100[k] = v100;
      S100 += v100;
      U100 += v100 * e100;
    }
#pragma unroll
    for (int off = 1; off < 64; off <<= 1) {
      S1 += __shfl_xor(S1, off, 64);
      S100 += __shfl_xor(S100, off, 64);
      U100 += __shfl_xor(U100, off, 64);
    }
    float invS1 = 1.0f / S1;
    float invS100 = 1.0f / S100;
    if (lane == 0) entp += __logf(S100) - U100 * invS100;
#pragma unroll
    for (int kj = 0; kj < 4; ++kj) {
      ushort4 pk;
      pk.x = f2bf(E1[kj * 4 + 0] * invS1);
      pk.y = f2bf(E1[kj * 4 + 1] * invS1);
      pk.z = f2bf(E1[kj * 4 + 2] * invS1);
      pk.w = f2bf(E1[kj * 4 + 3] * invS1);
      *(ushort4*)&att[(size_t)row * K_ + lane * 4 + kj * 256] = pk;
      p_loc[kj * 4 + 0] += E100[kj * 4 + 0] * invS100;
      p_loc[kj * 4 + 1] += E100[kj * 4 + 1] * invS100;
      p_loc[kj * 4 + 2] += E100[kj * 4 + 2] * invS100;
      p_loc[kj * 4 + 3] += E100[kj * 4 + 3] * invS100;
    }
  }
  // deferred exact rechecks, back-to-back for x-line reuse
  int nrow = r0 >> 10;   // block spans one n
  while (defer) {
    int i = __ffs(defer) - 1;
    defer &= defer - 1;
    int row = r0 + wv * 8 + i;
    int trow = row & 1023;
    float xr[8];
#pragma unroll
    for (int u = 0; u < 8; ++u)
      xr[u] = x[(((size_t)(nrow * 512 + lane + u * 64)) << 10) + trow];
    int cnt = cnt_s[wv][i];
    if (cnt > 16) cnt = 16;
    float best = -1e30f;
    int bi = K_;
    for (int it = 0; it < cnt; ++it) {
      int j = cand_s[wv][i][it];
      const float* mrow = &MT[((size_t)j) << 9];
      float sd = 0.f;
#pragma unroll
      for (int u = 0; u < 8; ++u) sd = fmaf(xr[u], mrow[lane + u * 64], sd);
#pragma unroll
      for (int off = 1; off < 64; off <<= 1) sd += __shfl_xor(sd, off, 64);
      if (sd > best || (sd == best && j < bi)) { best = sd; bi = j; }
    }
    if (lane == 0) {
      out[CODE_OFF + row] = (float)bi;
      atomicAdd(&counts[bi], 1.0f);
    }
  }
#pragma unroll
  for (int kj = 0; kj < 4; ++kj)
#pragma unroll
    for (int kl = 0; kl < 4; ++kl)
      atomicAdd(&avg_s[lane * 4 + kl + 256 * kj], p_loc[kj * 4 + kl]);
  if (lane == 0) atomicAdd(&red_s, entp);
  __syncthreads();
  if (tid == 0) atomicAdd(&scal[0], red_s);
  for (int i = tid; i < K_; i += 256) atomicAdd(&avg_probs[i], avg_s[i]);
}

// zq v4: round-6 body (launch_bounds reverted) + XCD-aware mapping: each
// XCD's sequence groups a panel's 4 y-tiles back-to-back -> att panel
// (256 KB) stays L2-hot across its 4 uses.
__global__ __launch_bounds__(256) void zq_kernel(const float* __restrict__ x,
                                                 const unsigned short* __restrict__ att,
                                                 const unsigned short* __restrict__ cbt,
                                                 float* __restrict__ out,
                                                 float* __restrict__ scal) {
  __shared__ __align__(16) unsigned char As[16384];   // [128 rows][128 B] swizzled
  __shared__ __align__(16) unsigned char Bs[16384];
  int tid = threadIdx.x;
  int wv = tid >> 6, lane = tid & 63;
  int wr = wv >> 1, wc = wv & 1;
  int bid = blockIdx.x;                 // 2048 = 512 panels x 4 y-tiles
  int i = bid >> 3;                     // per-XCD sequence 0..255
  int xl = i >> 2, y = i & 3;           // panel-local, y-tile
  int r0 = (((bid & 7) << 6) + xl) * 128;
  const char* Abyte = (const char*)(att + (size_t)r0 * K_);
  const char* Bbyte = (const char*)(cbt + (size_t)(y * 128) * K_);

  int srow[4], skb[4];
#pragma unroll
  for (int r = 0; r < 4; ++r) {
    int d = r * 4096 + wv * 1024 + lane * 16;
    srow[r] = d >> 7;
    skb[r] = (d & 127) ^ ((srow[r] & 7) << 4);
  }

  int ll = lane & 15, lh2 = ((lane >> 4) * 8) * 2;
  int arowb[4], axm[4], browb[4], bxm[4];
#pragma unroll
  for (int t = 0; t < 4; ++t) {
    int ar = wr * 64 + t * 16 + ll;
    arowb[t] = ar * 128; axm[t] = (ar & 7) << 4;
    int br = wc * 64 + t * 16 + ll;
    browb[t] = br * 128; bxm[t] = (br & 7) << 4;
  }

  f32x4 acc[4][4] = {};
  for (int k0 = 0; k0 < 1024; k0 += 64) {
    __syncthreads();
#pragma unroll
    for (int r = 0; r < 4; ++r)
      gl_lds16(Abyte + (size_t)srow[r] * 2048 + (size_t)k0 * 2 + skb[r],
               As + r * 4096 + wv * 1024);
#pragma unroll
    for (int r = 0; r < 4; ++r)
      gl_lds16(Bbyte + (size_t)srow[r] * 2048 + (size_t)k0 * 2 + skb[r],
               Bs + r * 4096 + wv * 1024);
    __syncthreads();
#pragma unroll
    for (int kk = 0; kk < 2; ++kk) {
      int kb = kk * 64 + lh2;
      short8 af[4], bf[4];
#pragma unroll
      for (int rt = 0; rt < 4; ++rt)
        af[rt] = *(const short8*)(As + arowb[rt] + (kb ^ axm[rt]));
#pragma unroll
      for (int ct = 0; ct < 4; ++ct)
        bf[ct] = *(const short8*)(Bs + browb[ct] + (kb ^ bxm[ct]));
#pragma unroll
      for (int rt = 0; rt < 4; ++rt)
#pragma unroll
        for (int ct = 0; ct < 4; ++ct)
          acc[rt][ct] = __builtin_amdgcn_mfma_f32_16x16x32_bf16(af[rt], bf[ct], acc[rt][ct], 0, 0, 0);
    }
  }

  // epilogue: row = r0 + wr*64 + rt*16 + (lane>>4)*4 + reg; col c = y*128 + wc*64 + ct*16 + ll
  int nb = r0 >> 10, t0 = (r0 & 1023) + wr * 64;
  float vqp = 0.f;
#pragma unroll
  for (int rt = 0; rt < 4; ++rt) {
    int t = t0 + rt * 16 + (lane >> 4) * 4;
#pragma unroll
    for (int ct = 0; ct < 4; ++ct) {
      int c = y * 128 + wc * 64 + ct * 16 + ll;
      size_t xi = (size_t)nb * C_ * T_ + (size_t)c * T_ + t;
      float4 xv = *(const float4*)&x[xi];
      float4 z = make_float4(acc[rt][ct][0], acc[rt][ct][1], acc[rt][ct][2], acc[rt][ct][3]);
      float d0 = z.x - xv.x, d1 = z.y - xv.y, d2 = z.z - xv.z, d3 = z.w - xv.w;
      vqp += d0 * d0 + d1 * d1 + d2 * d2 + d3 * d3;
      *(float4*)&out[XD_OFF + xi] = z;
    }
  }
#pragma unroll
  for (int off = 1; off < 64; off <<= 1) vqp += __shfl_xor(vqp, off, 64);
  if (lane == 0) atomicAdd(&scal[1], vqp);
}

__global__ __launch_bounds__(1024) void finalize_kernel(const float* __restrict__ avgp,
                                                        const float* __restrict__ counts,
                                                        const float* __restrict__ scal,
                                                        float* __restrict__ out) {
  __shared__ float r1[16], r2[16];
  int tid = threadIdx.x;
  float a = avgp[tid] * (1.0f / 65536.0f);
  float t1 = a * logf(a + 1e-5f);
  float p = counts[tid] * (1.0f / 65536.0f);
  float t2 = p * logf(p + 1e-7f);
#pragma unroll
  for (int off = 1; off < 64; off <<= 1) {
    t1 += __shfl_xor(t1, off, 64);
    t2 += __shfl_xor(t2, off, 64);
  }
  int wv = tid >> 6, lane = tid & 63;
  if (lane == 0) { r1[wv] = t1; r2[wv] = t2; }
  __syncthreads();
  if (tid == 0) {
    float T1 = 0.f, T2 = 0.f;
    for (int i = 0; i < 16; ++i) { T1 += r1[i]; T2 += r2[i]; }
    float sample_entropy = scal[0] * (1.0f / 65536.0f);
    float avg_entropy = -T1;
    out[SC_OFF + 0] = sample_entropy;
    out[SC_OFF + 1] = avg_entropy;
    out[SC_OFF + 2] = sample_entropy - avg_entropy;
    out[SC_OFF + 3] = expf(-T2);
    out[SC_OFF + 4] = scal[1] * (1.0f / 33554432.0f);
  }
}

extern "C" void kernel_launch(void* const* d_in, const int* in_sizes, int n_in,
                              void* d_out, int out_size, void* d_ws, size_t ws_size,
                              hipStream_t stream) {
  const float* x  = (const float*)d_in[0];
  const float* cb = (const float*)d_in[1];
  const float* Wq = (const float*)d_in[2];
  const float* Wk = (const float*)d_in[3];
  float* out = (float*)d_out;
  float* ws = (float*)d_ws;

  unsigned short* xhT = (unsigned short*)ws;            // bf16 [NT][512]
  unsigned short* att = (unsigned short*)ws;            // bf16 [NT][1024] (alias, post-d_kernel)
  unsigned short* MhT = (unsigned short*)(ws + MHT_OFF);
  float* MT           = ws + MT_OFF;
  unsigned short* WqhT = (unsigned short*)(ws + WQH_OFF);
  float* kn           = ws + KN_OFF;
  unsigned short* cbt = (unsigned short*)(ws + CBT_OFF);
  float* nsq          = ws + NSQ_OFF;
  float* avgp         = ws + AVG_OFF;
  float* counts       = ws + CNT_OFF;
  float* scal         = ws + SCAL_OFF;
  _Float16* D16       = (_Float16*)d_out;               // fp16 [NT][1024] == XD region

  init_kernel<<<256, 256, 0, stream>>>(avgp, nsq);
  knorm_kernel<<<K_ / 4, 256, 0, stream>>>(cb, Wk, kn);
  m_kernel<<<K_ / 4, 256, 0, stream>>>(Wq, kn, MhT, MT);
  wqht_kernel<<<1024, 256, 0, stream>>>(Wq, WqhT);
  cbt_kernel<<<(C_ * K_) / 256, 256, 0, stream>>>(cb, cbt);
  xsplit_kernel<<<1024, 256, 0, stream>>>(x, xhT);
  d_kernel<<<6144, 256, 0, stream>>>(xhT, MhT, WqhT, D16, nsq);
  stats_kernel<<<NT_ / 32, 256, 0, stream>>>(x, D16, nsq, MT, att, out, avgp, counts, scal);
  zq_kernel<<<2048, 256, 0, stream>>>(x, att, cbt, out, scal);
  finalize_kernel<<<1, 1024, 0, stream>>>(avgp, counts, scal, out);
}

// Round 10
// 828.421 us; speedup vs baseline: 1.1382x; 1.0209x over previous
//
#include <hip/hip_runtime.h>
#include <hip/hip_bf16.h>

// Problem dims (fixed by reference)
constexpr int N_ = 64, C_ = 512, T_ = 1024;
constexpr int NT_ = N_ * T_;        // 65536 rows
constexpr int K_ = 1024;            // nb_code
constexpr int A_ = 512;             // attn_dim

// Output layout (floats, concatenated in return order)
constexpr size_t XD_OFF   = 0;                       // 33554432 floats
constexpr size_t SC_OFF   = (size_t)N_ * C_ * T_;    // 5 scalars
constexpr size_t CODE_OFF = SC_OFF + 5;              // 65536 code_idx as float
// NOTE: D~ (fp16 [NT][1024] = 134217728 B) EXACTLY fits the XD region of d_out.
// It is written by d_kernel, consumed by stats_kernel, then zq_kernel
// overwrites the region with x_d (stream-ordered, same launch).

// Workspace layout (floats)
// region0 (128 MB): xhT bf16 [NT][512] (first 64 MB); att bf16 [NT][1024]
//   aliases the same base — xhT is dead once stats_kernel (which writes att)
//   runs, and d_kernel (the only xhT reader) fully precedes it.
constexpr size_t MHT_OFF  = 33554432;                 // MhT bf16 [1024][512]
constexpr size_t MT_OFF   = MHT_OFF + 262144;         // MT fp32 [1024][512]
constexpr size_t WQH_OFF  = MT_OFF + 524288;          // WqhT bf16 [512][512]
constexpr size_t KN_OFF   = WQH_OFF + 131072;         // kn fp32 [1024][512]
constexpr size_t CBT_OFF  = KN_OFF + 524288;          // cbt bf16 [512][1024]
constexpr size_t NSQ_OFF  = CBT_OFF + 262144;         // normsq fp32 [65536]
constexpr size_t AVG_OFF  = NSQ_OFF + 65536;
constexpr size_t CNT_OFF  = AVG_OFF + 1024;
constexpr size_t SCAL_OFF = CNT_OFF + 1024;           // [0]=ent_sum, [1]=vq_sum

typedef __attribute__((ext_vector_type(8))) short short8;
typedef __attribute__((ext_vector_type(4))) float f32x4;
typedef _Float16 h4 __attribute__((ext_vector_type(4)));

__device__ __forceinline__ unsigned short f2bf(float f) {
  unsigned int u = __float_as_uint(f);
  unsigned int r = (u + 0x7fffu + ((u >> 16) & 1u)) >> 16;
  return (unsigned short)r;
}

// async global->LDS, 16B/lane. LDS dest must be wave-uniform base (HW adds lane*16).
__device__ __forceinline__ void gl_lds16(const void* g, void* l) {
  __builtin_amdgcn_global_load_lds(
      (const __attribute__((address_space(1))) unsigned int*)g,
      (__attribute__((address_space(3))) unsigned int*)l, 16, 0, 0);
}

__global__ __launch_bounds__(256) void init_kernel(float* small, float* nsq) {
  int i = blockIdx.x * 256 + threadIdx.x;
  if (i < 2050) small[i] = 0.f;     // avg_probs + counts + 2 scalars
  if (i < NT_) nsq[i] = 0.f;
}

// kn = l2norm(codebook @ Wk), row-major [1024][512] (NO 1/sqrt(A) fold)
__global__ __launch_bounds__(256) void knorm_kernel(const float* __restrict__ cb,
                                                    const float* __restrict__ Wk,
                                                    float* __restrict__ kn) {
  __shared__ float cb_s[4][A_];
  __shared__ float norm_s[4];
  int tid = threadIdx.x;
  int r0 = blockIdx.x * 4;
  for (int i = tid; i < 4 * A_; i += 256) {
    int r = i >> 9, c = i & 511;
    cb_s[r][c] = cb[(size_t)(r0 + r) * C_ + c];
  }
  if (tid < 4) norm_s[tid] = 0.f;
  __syncthreads();
  float acc[4][2] = {};
  for (int c = 0; c < C_; ++c) {
    float w0 = Wk[(size_t)c * A_ + tid];
    float w1 = Wk[(size_t)c * A_ + tid + 256];
#pragma unroll
    for (int r = 0; r < 4; ++r) {
      float xv = cb_s[r][c];
      acc[r][0] += xv * w0;
      acc[r][1] += xv * w1;
    }
  }
#pragma unroll
  for (int r = 0; r < 4; ++r) {
    float ss = acc[r][0] * acc[r][0] + acc[r][1] * acc[r][1];
#pragma unroll
    for (int off = 32; off > 0; off >>= 1) ss += __shfl_down(ss, off, 64);
    if ((tid & 63) == 0) atomicAdd(&norm_s[r], ss);
  }
  __syncthreads();
#pragma unroll
  for (int r = 0; r < 4; ++r) {
    float scale = 1.0f / (sqrtf(norm_s[r]) + 1e-8f);
    kn[(size_t)(r0 + r) * A_ + tid] = acc[r][0] * scale;
    kn[(size_t)(r0 + r) * A_ + tid + 256] = acc[r][1] * scale;
  }
}

// M = Wq @ kn^T  (fp64 accumulate), outputs MhT bf16 [j][c] and MT fp32 [j][c]
__global__ __launch_bounds__(256) void m_kernel(const float* __restrict__ Wq,
                                                const float* __restrict__ kn,
                                                unsigned short* __restrict__ MhT,
                                                float* __restrict__ MT) {
  __shared__ float kn_s[4][512];
  int tid = threadIdx.x;
  int j0 = blockIdx.x * 4;
  for (int i = tid; i < 4 * 512; i += 256) {
    int jj = i >> 9, a = i & 511;
    kn_s[jj][a] = kn[(size_t)(j0 + jj) * 512 + a];
  }
  __syncthreads();
  double acc[2][4] = {};
  for (int a0 = 0; a0 < 512; a0 += 4) {
    float4 w0 = *(const float4*)&Wq[(size_t)tid * 512 + a0];
    float4 w1 = *(const float4*)&Wq[(size_t)(tid + 256) * 512 + a0];
#pragma unroll
    for (int jj = 0; jj < 4; ++jj) {
      float4 kv = *(float4*)&kn_s[jj][a0];
      acc[0][jj] += (double)w0.x * kv.x + (double)w0.y * kv.y +
                    (double)w0.z * kv.z + (double)w0.w * kv.w;
      acc[1][jj] += (double)w1.x * kv.x + (double)w1.y * kv.y +
                    (double)w1.z * kv.z + (double)w1.w * kv.w;
    }
  }
#pragma unroll
  for (int jj = 0; jj < 4; ++jj) {
    int j = j0 + jj;
    float m0 = (float)acc[0][jj], m1 = (float)acc[1][jj];
    MhT[(size_t)j * 512 + tid] = f2bf(m0);
    MhT[(size_t)j * 512 + tid + 256] = f2bf(m1);
    MT[(size_t)j * 512 + tid] = m0;
    MT[(size_t)j * 512 + tid + 256] = m1;
  }
}

// WqhT[j][c] = bf16(Wq[c][j])
__global__ __launch_bounds__(256) void wqht_kernel(const float* __restrict__ Wq,
                                                   unsigned short* __restrict__ WqhT) {
  int idx = blockIdx.x * 256 + threadIdx.x;   // 262144
  int j = idx >> 9, c = idx & 511;
  WqhT[idx] = f2bf(Wq[(size_t)c * 512 + j]);
}

// cbT[c][k] = bf16(cb[k][c]) — B operand for the z_q MFMA
__global__ __launch_bounds__(256) void cbt_kernel(const float* __restrict__ cb,
                                                  unsigned short* __restrict__ cbt) {
  int idx = blockIdx.x * 256 + threadIdx.x;   // 524288 total
  int c = idx >> 10, k = idx & 1023;
  cbt[(size_t)c * K_ + k] = f2bf(cb[(size_t)k * C_ + c]);
}

// xhT[row][c] = bf16(x[n][c][t]),  row = n*1024 + t  (LDS transpose)
__global__ __launch_bounds__(256) void xsplit_kernel(const float* __restrict__ x,
                                                     unsigned short* __restrict__ xhT) {
  __shared__ float tile[64][65];
  int tid = threadIdx.x;
  int n = blockIdx.x >> 4;
  int t0 = (blockIdx.x & 15) * 64;
  for (int c0 = 0; c0 < 512; c0 += 64) {
    __syncthreads();
    {
      int t = tid & 63, cg = tid >> 6;
#pragma unroll
      for (int cl = 0; cl < 16; ++cl) {
        int cc = cl * 4 + cg;
        tile[cc][t] = x[(((size_t)(n * 512 + c0 + cc)) << 10) + t0 + t];
      }
    }
    __syncthreads();
    {
      int c = tid & 63, tg = tid >> 6;
#pragma unroll
      for (int tl = 0; tl < 16; ++tl) {
        int tt = tl * 4 + tg;
        xhT[(((size_t)(n * 1024 + t0 + tt)) << 9) + c0 + c] = f2bf(tile[c][tt]);
      }
    }
  }
}

// d_kernel v5: m97-structure GEMM (round-6 body, launch_bounds reverted) with
// XCD-aware block mapping (T1). Round-robin bid->XCD (bid&7); each XCD's
// local sequence i=bid>>3 enumerates its 64 A-panels with the panel's 12
// y-tiles BACK-TO-BACK -> ~5 concurrent panels x 131 KB = 0.7 MB per 4 MB
// XCD-L2 -> each panel fetched from HBM once (A-traffic 400->~64 MB).
// Math identical; mapping is perf-only (any XCD assignment stays correct).
__global__ __launch_bounds__(256) void d_kernel(const unsigned short* __restrict__ xhT,
                                                const unsigned short* __restrict__ MhT,
                                                const unsigned short* __restrict__ WqhT,
                                                _Float16* __restrict__ D16,
                                                float* __restrict__ nsq) {
  __shared__ __align__(16) unsigned char As[16384];   // [128 rows][128 B] swizzled
  __shared__ __align__(16) unsigned char Bs[16384];
  int tid = threadIdx.x;
  int wv = tid >> 6, lane = tid & 63;
  int wr = wv >> 1, wc = wv & 1;
  int bid = blockIdx.x;                 // 6144 = 512 panels x 12 y-tiles
  int i = bid >> 3;                     // per-XCD sequence 0..767
  int xl = i / 12, y = i - xl * 12;     // panel-local, y-tile
  int r0 = ((bid & 7) * 64 + xl) * 128; // panel rows
  bool isq = (y >= 8);
  const unsigned short* Bsrc = isq ? (WqhT + ((size_t)(y - 8) * 128) * 512)
                                   : (MhT + ((size_t)y * 128) * 512);
  const char* Abyte = (const char*)xhT;
  const char* Bbyte = (const char*)Bsrc;

  // staging geometry (k0-independent): per round r, this lane fills LDS phys
  // offset d = r*4096 + wv*1024 + lane*16 -> tile row = d>>7, byte-in-row
  // kb = d&127; the logical k-byte stored there is kb ^ ((row&7)<<4).
  int srow[4], skb[4];
#pragma unroll
  for (int r = 0; r < 4; ++r) {
    int d = r * 4096 + wv * 1024 + lane * 16;
    srow[r] = d >> 7;
    skb[r] = (d & 127) ^ ((srow[r] & 7) << 4);
  }

  // fragment geometry: lane ll reads row rt*16+ll (within wave's 64-row strip),
  // k elements lh..lh+7
  int ll = lane & 15, lh2 = ((lane >> 4) * 8) * 2;   // byte offset of k-group
  int arowb[4], axm[4], browb[4], bxm[4];
#pragma unroll
  for (int t = 0; t < 4; ++t) {
    int ar = wr * 64 + t * 16 + ll;
    arowb[t] = ar * 128; axm[t] = (ar & 7) << 4;
    int br = wc * 64 + t * 16 + ll;
    browb[t] = br * 128; bxm[t] = (br & 7) << 4;
  }

  f32x4 acc[4][4] = {};
  for (int k0 = 0; k0 < 512; k0 += 64) {
    __syncthreads();   // previous K-step's reads complete before overwrite
#pragma unroll
    for (int r = 0; r < 4; ++r)
      gl_lds16(Abyte + (size_t)(r0 + srow[r]) * 1024 + (size_t)k0 * 2 + skb[r],
               As + r * 4096 + wv * 1024);
#pragma unroll
    for (int r = 0; r < 4; ++r)
      gl_lds16(Bbyte + (size_t)srow[r] * 1024 + (size_t)k0 * 2 + skb[r],
               Bs + r * 4096 + wv * 1024);
    __syncthreads();   // compiler drains vmcnt before barrier -> data landed
#pragma unroll
    for (int kk = 0; kk < 2; ++kk) {
      int kb = kk * 64 + lh2;          // logical k-byte of this lane's group
      short8 af[4], bf[4];
#pragma unroll
      for (int rt = 0; rt < 4; ++rt)
        af[rt] = *(const short8*)(As + arowb[rt] + (kb ^ axm[rt]));
#pragma unroll
      for (int ct = 0; ct < 4; ++ct)
        bf[ct] = *(const short8*)(Bs + browb[ct] + (kb ^ bxm[ct]));
#pragma unroll
      for (int rt = 0; rt < 4; ++rt)
#pragma unroll
        for (int ct = 0; ct < 4; ++ct)
          acc[rt][ct] = __builtin_amdgcn_mfma_f32_16x16x32_bf16(af[rt], bf[ct], acc[rt][ct], 0, 0, 0);
    }
  }

  // C/D layout: col = ct*16 + ll, row = rt*16 + (lane>>4)*4 + reg (per 64x64)
  if (!isq) {
    int cbase = y * 128 + wc * 64;
#pragma unroll
    for (int rt = 0; rt < 4; ++rt)
#pragma unroll
      for (int ct = 0; ct < 4; ++ct) {
        int col = cbase + ct * 16 + ll;
#pragma unroll
        for (int reg = 0; reg < 4; ++reg) {
          int row = r0 + wr * 64 + rt * 16 + (lane >> 4) * 4 + reg;
          D16[(size_t)row * 1024 + col] = (_Float16)acc[rt][ct][reg];
        }
      }
  } else {
#pragma unroll
    for (int rt = 0; rt < 4; ++rt)
#pragma unroll
      for (int reg = 0; reg < 4; ++reg) {
        float sq = 0.f;
#pragma unroll
        for (int ct = 0; ct < 4; ++ct) { float v = acc[rt][ct][reg]; sq += v * v; }
        sq += __shfl_xor(sq, 1, 64);
        sq += __shfl_xor(sq, 2, 64);
        sq += __shfl_xor(sq, 4, 64);
        sq += __shfl_xor(sq, 8, 64);
        if (ll == 0)
          atomicAdd(&nsq[r0 + wr * 64 + rt * 16 + (lane >> 4) * 4 + reg], sq);
      }
  }
}

// Stats v5: v4 + (a) D16 row software-prefetch (load row i+1's 4x h4 while
// row i's softmax math runs — hides ~900cy HBM latency under VALU work);
// (b) __syncthreads() before the deferred-recheck epilogue: waves {0,1} and
// {2,3} of a block need IDENTICAL 512 x-lines (64B line spans 16 t; t0 is
// 32-aligned); synchronizing the gathers makes the pair's second gather
// L1/L2-hot, halving x HBM traffic (~236 -> ~128 MB).
__global__ __launch_bounds__(256) void stats_kernel(
    const float* __restrict__ x, const _Float16* __restrict__ D16,
    const float* __restrict__ nsq, const float* __restrict__ MT,
    unsigned short* __restrict__ att, float* __restrict__ out,
    float* __restrict__ avg_probs, float* __restrict__ counts,
    float* __restrict__ scal) {
  __shared__ float avg_s[K_];
  __shared__ float red_s;
  __shared__ short cand_s[4][8][16];
  __shared__ int cnt_s[4][8];
  int tid = threadIdx.x;
  int wv = tid >> 6, lane = tid & 63;
  int r0 = blockIdx.x * 32;
  for (int i = tid; i < K_; i += 256) avg_s[i] = 0.f;
  if (tid == 0) red_s = 0.f;
  __syncthreads();

  float entp = 0.f;
  float p_loc[16] = {};
  unsigned defer = 0u;   // wave-uniform bitmask of deferred rows
  // preload row 0's D16 vectors
  h4 cur[4];
#pragma unroll
  for (int kj = 0; kj < 4; ++kj)
    cur[kj] = *(const h4*)&D16[(size_t)(r0 + wv * 8) * 1024 + lane * 4 + kj * 256];
  for (int i = 0; i < 8; ++i) {
    int row = r0 + wv * 8 + i;
    float s = 1.0f / ((sqrtf(nsq[row]) + 1e-8f) * 22.62741699796952f);
    // logits from preloaded vectors (16 per lane: kk = lane*4 + kl + 256*kj)
    float l[16];
#pragma unroll
    for (int kj = 0; kj < 4; ++kj)
#pragma unroll
      for (int u = 0; u < 4; ++u) l[kj * 4 + u] = (float)cur[kj][u] * s;
    // issue next row's loads early (hide HBM latency under this row's math)
    if (i < 7) {
#pragma unroll
      for (int kj = 0; kj < 4; ++kj)
        cur[kj] = *(const h4*)&D16[(size_t)(row + 1) * 1024 + lane * 4 + kj * 256];
    }
    // single value-only wave max
    float m0 = l[0];
#pragma unroll
    for (int k = 1; k < 16; ++k) m0 = fmaxf(m0, l[k]);
#pragma unroll
    for (int off = 1; off < 64; off <<= 1) m0 = fmaxf(m0, __shfl_xor(m0, off, 64));
    // candidate mask within the value window
    float thr = m0 - 3.0e-4f;
    unsigned cmask = 0u;
#pragma unroll
    for (int k = 0; k < 16; ++k) cmask |= (l[k] >= thr) ? (1u << k) : 0u;
    int pc = __popc(cmask);
    unsigned long long b1 = __ballot(pc != 0);
    unsigned long long b2 = __ballot(pc > 1);
    if (b2 == 0ull && __popcll(b1) == 1) {
      // unique candidate wave-wide == argmax (window >> approx error bound)
      int b = __ffs(cmask) - 1;                       // valid on owner lane
      int kk = lane * 4 + (b & 3) + 256 * (b >> 2);
      int bi = __shfl(kk, (int)(__ffsll(b1) - 1), 64);
      if (lane == 0) {
        out[CODE_OFF + row] = (float)bi;
        atomicAdd(&counts[bi], 1.0f);
      }
    } else {
      // record candidates; exact recheck deferred to block-synced epilogue
      if (lane == 0) cnt_s[wv][i] = 0;
      int base = 0;
      if (pc) base = atomicAdd(&cnt_s[wv][i], pc);    // same-wave LDS: in-order
      unsigned mrem = cmask;
      for (int t2 = 0; t2 < pc; ++t2) {
        int b = __ffs(mrem) - 1;
        mrem &= mrem - 1;
        int slot = base + t2;
        if (slot < 16)
          cand_s[wv][i][slot] = (short)(lane * 4 + (b & 3) + 256 * (b >> 2));
      }
      defer |= 1u << i;
    }
    // softmax stats (shift by m0), exps computed once and cached
    float E1[16], E100[16];
    float S1 = 0.f, S100 = 0.f, U100 = 0.f;
#pragma unroll
    for (int k = 0; k < 16; ++k) {
      float e = l[k] - m0;
      float v1 = __expf(e);
      E1[k] = v1;
      S1 += v1;
      float e100 = e * 100.0f;
      float v100 = __expf(e100);
      E100[k] = v100;
      S100 += v100;
      U100 += v100 * e100;
    }
#pragma unroll
    for (int off = 1; off < 64; off <<= 1) {
      S1 += __shfl_xor(S1, off, 64);
      S100 += __shfl_xor(S100, off, 64);
      U100 += __shfl_xor(U100, off, 64);
    }
    float invS1 = 1.0f / S1;
    float invS100 = 1.0f / S100;
    if (lane == 0) entp += __logf(S100) - U100 * invS100;
#pragma unroll
    for (int kj = 0; kj < 4; ++kj) {
      ushort4 pk;
      pk.x = f2bf(E1[kj * 4 + 0] * invS1);
      pk.y = f2bf(E1[kj * 4 + 1] * invS1);
      pk.z = f2bf(E1[kj * 4 + 2] * invS1);
      pk.w = f2bf(E1[kj * 4 + 3] * invS1);
      *(ushort4*)&att[(size_t)row * K_ + lane * 4 + kj * 256] = pk;
      p_loc[kj * 4 + 0] += E100[kj * 4 + 0] * invS100;
      p_loc[kj * 4 + 1] += E100[kj * 4 + 1] * invS100;
      p_loc[kj * 4 + 2] += E100[kj * 4 + 2] * invS100;
      p_loc[kj * 4 + 3] += E100[kj * 4 + 3] * invS100;
    }
  }
  // align all waves so their x-gathers coincide: paired waves share the same
  // 512 cache lines -> second gather hits L1/L2 instead of HBM.
  __syncthreads();
  // deferred exact rechecks, back-to-back for x-line reuse
  int nrow = r0 >> 10;   // block spans one n
  while (defer) {
    int i = __ffs(defer) - 1;
    defer &= defer - 1;
    int row = r0 + wv * 8 + i;
    int trow = row & 1023;
    float xr[8];
#pragma unroll
    for (int u = 0; u < 8; ++u)
      xr[u] = x[(((size_t)(nrow * 512 + lane + u * 64)) << 10) + trow];
    int cnt = cnt_s[wv][i];
    if (cnt > 16) cnt = 16;
    float best = -1e30f;
    int bi = K_;
    for (int it = 0; it < cnt; ++it) {
      int j = cand_s[wv][i][it];
      const float* mrow = &MT[((size_t)j) << 9];
      float sd = 0.f;
#pragma unroll
      for (int u = 0; u < 8; ++u) sd = fmaf(xr[u], mrow[lane + u * 64], sd);
#pragma unroll
      for (int off = 1; off < 64; off <<= 1) sd += __shfl_xor(sd, off, 64);
      if (sd > best || (sd == best && j < bi)) { best = sd; bi = j; }
    }
    if (lane == 0) {
      out[CODE_OFF + row] = (float)bi;
      atomicAdd(&counts[bi], 1.0f);
    }
  }
#pragma unroll
  for (int kj = 0; kj < 4; ++kj)
#pragma unroll
    for (int kl = 0; kl < 4; ++kl)
      atomicAdd(&avg_s[lane * 4 + kl + 256 * kj], p_loc[kj * 4 + kl]);
  if (lane == 0) atomicAdd(&red_s, entp);
  __syncthreads();
  if (tid == 0) atomicAdd(&scal[0], red_s);
  for (int i = tid; i < K_; i += 256) atomicAdd(&avg_probs[i], avg_s[i]);
}

// zq v4: round-6 body (launch_bounds reverted) + XCD-aware mapping: each
// XCD's sequence groups a panel's 4 y-tiles back-to-back -> att panel
// (256 KB) stays L2-hot across its 4 uses.
__global__ __launch_bounds__(256) void zq_kernel(const float* __restrict__ x,
                                                 const unsigned short* __restrict__ att,
                                                 const unsigned short* __restrict__ cbt,
                                                 float* __restrict__ out,
                                                 float* __restrict__ scal) {
  __shared__ __align__(16) unsigned char As[16384];   // [128 rows][128 B] swizzled
  __shared__ __align__(16) unsigned char Bs[16384];
  int tid = threadIdx.x;
  int wv = tid >> 6, lane = tid & 63;
  int wr = wv >> 1, wc = wv & 1;
  int bid = blockIdx.x;                 // 2048 = 512 panels x 4 y-tiles
  int i = bid >> 3;                     // per-XCD sequence 0..255
  int xl = i >> 2, y = i & 3;           // panel-local, y-tile
  int r0 = (((bid & 7) << 6) + xl) * 128;
  const char* Abyte = (const char*)(att + (size_t)r0 * K_);
  const char* Bbyte = (const char*)(cbt + (size_t)(y * 128) * K_);

  int srow[4], skb[4];
#pragma unroll
  for (int r = 0; r < 4; ++r) {
    int d = r * 4096 + wv * 1024 + lane * 16;
    srow[r] = d >> 7;
    skb[r] = (d & 127) ^ ((srow[r] & 7) << 4);
  }

  int ll = lane & 15, lh2 = ((lane >> 4) * 8) * 2;
  int arowb[4], axm[4], browb[4], bxm[4];
#pragma unroll
  for (int t = 0; t < 4; ++t) {
    int ar = wr * 64 + t * 16 + ll;
    arowb[t] = ar * 128; axm[t] = (ar & 7) << 4;
    int br = wc * 64 + t * 16 + ll;
    browb[t] = br * 128; bxm[t] = (br & 7) << 4;
  }

  f32x4 acc[4][4] = {};
  for (int k0 = 0; k0 < 1024; k0 += 64) {
    __syncthreads();
#pragma unroll
    for (int r = 0; r < 4; ++r)
      gl_lds16(Abyte + (size_t)srow[r] * 2048 + (size_t)k0 * 2 + skb[r],
               As + r * 4096 + wv * 1024);
#pragma unroll
    for (int r = 0; r < 4; ++r)
      gl_lds16(Bbyte + (size_t)srow[r] * 2048 + (size_t)k0 * 2 + skb[r],
               Bs + r * 4096 + wv * 1024);
    __syncthreads();
#pragma unroll
    for (int kk = 0; kk < 2; ++kk) {
      int kb = kk * 64 + lh2;
      short8 af[4], bf[4];
#pragma unroll
      for (int rt = 0; rt < 4; ++rt)
        af[rt] = *(const short8*)(As + arowb[rt] + (kb ^ axm[rt]));
#pragma unroll
      for (int ct = 0; ct < 4; ++ct)
        bf[ct] = *(const short8*)(Bs + browb[ct] + (kb ^ bxm[ct]));
#pragma unroll
      for (int rt = 0; rt < 4; ++rt)
#pragma unroll
        for (int ct = 0; ct < 4; ++ct)
          acc[rt][ct] = __builtin_amdgcn_mfma_f32_16x16x32_bf16(af[rt], bf[ct], acc[rt][ct], 0, 0, 0);
    }
  }

  // epilogue: row = r0 + wr*64 + rt*16 + (lane>>4)*4 + reg; col c = y*128 + wc*64 + ct*16 + ll
  int nb = r0 >> 10, t0 = (r0 & 1023) + wr * 64;
  float vqp = 0.f;
#pragma unroll
  for (int rt = 0; rt < 4; ++rt) {
    int t = t0 + rt * 16 + (lane >> 4) * 4;
#pragma unroll
    for (int ct = 0; ct < 4; ++ct) {
      int c = y * 128 + wc * 64 + ct * 16 + ll;
      size_t xi = (size_t)nb * C_ * T_ + (size_t)c * T_ + t;
      float4 xv = *(const float4*)&x[xi];
      float4 z = make_float4(acc[rt][ct][0], acc[rt][ct][1], acc[rt][ct][2], acc[rt][ct][3]);
      float d0 = z.x - xv.x, d1 = z.y - xv.y, d2 = z.z - xv.z, d3 = z.w - xv.w;
      vqp += d0 * d0 + d1 * d1 + d2 * d2 + d3 * d3;
      *(float4*)&out[XD_OFF + xi] = z;
    }
  }
#pragma unroll
  for (int off = 1; off < 64; off <<= 1) vqp += __shfl_xor(vqp, off, 64);
  if (lane == 0) atomicAdd(&scal[1], vqp);
}

__global__ __launch_bounds__(1024) void finalize_kernel(const float* __restrict__ avgp,
                                                        const float* __restrict__ counts,
                                                        const float* __restrict__ scal,
                                                        float* __restrict__ out) {
  __shared__ float r1[16], r2[16];
  int tid = threadIdx.x;
  float a = avgp[tid] * (1.0f / 65536.0f);
  float t1 = a * logf(a + 1e-5f);
  float p = counts[tid] * (1.0f / 65536.0f);
  float t2 = p * logf(p + 1e-7f);
#pragma unroll
  for (int off = 1; off < 64; off <<= 1) {
    t1 += __shfl_xor(t1, off, 64);
    t2 += __shfl_xor(t2, off, 64);
  }
  int wv = tid >> 6, lane = tid & 63;
  if (lane == 0) { r1[wv] = t1; r2[wv] = t2; }
  __syncthreads();
  if (tid == 0) {
    float T1 = 0.f, T2 = 0.f;
    for (int i = 0; i < 16; ++i) { T1 += r1[i]; T2 += r2[i]; }
    float sample_entropy = scal[0] * (1.0f / 65536.0f);
    float avg_entropy = -T1;
    out[SC_OFF + 0] = sample_entropy;
    out[SC_OFF + 1] = avg_entropy;
    out[SC_OFF + 2] = sample_entropy - avg_entropy;
    out[SC_OFF + 3] = expf(-T2);
    out[SC_OFF + 4] = scal[1] * (1.0f / 33554432.0f);
  }
}

extern "C" void kernel_launch(void* const* d_in, const int* in_sizes, int n_in,
                              void* d_out, int out_size, void* d_ws, size_t ws_size,
                              hipStream_t stream) {
  const float* x  = (const float*)d_in[0];
  const float* cb = (const float*)d_in[1];
  const float* Wq = (const float*)d_in[2];
  const float* Wk = (const float*)d_in[3];
  float* out = (float*)d_out;
  float* ws = (float*)d_ws;

  unsigned short* xhT = (unsigned short*)ws;            // bf16 [NT][512]
  unsigned short* att = (unsigned short*)ws;            // bf16 [NT][1024] (alias, post-d_kernel)
  unsigned short* MhT = (unsigned short*)(ws + MHT_OFF);
  float* MT           = ws + MT_OFF;
  unsigned short* WqhT = (unsigned short*)(ws + WQH_OFF);
  float* kn           = ws + KN_OFF;
  unsigned short* cbt = (unsigned short*)(ws + CBT_OFF);
  float* nsq          = ws + NSQ_OFF;
  float* avgp         = ws + AVG_OFF;
  float* counts       = ws + CNT_OFF;
  float* scal         = ws + SCAL_OFF;
  _Float16* D16       = (_Float16*)d_out;               // fp16 [NT][1024] == XD region

  init_kernel<<<256, 256, 0, stream>>>(avgp, nsq);
  knorm_kernel<<<K_ / 4, 256, 0, stream>>>(cb, Wk, kn);
  m_kernel<<<K_ / 4, 256, 0, stream>>>(Wq, kn, MhT, MT);
  wqht_kernel<<<1024, 256, 0, stream>>>(Wq, WqhT);
  cbt_kernel<<<(C_ * K_) / 256, 256, 0, stream>>>(cb, cbt);
  xsplit_kernel<<<1024, 256, 0, stream>>>(x, xhT);
  d_kernel<<<6144, 256, 0, stream>>>(xhT, MhT, WqhT, D16, nsq);
  stats_kernel<<<NT_ / 32, 256, 0, stream>>>(x, D16, nsq, MT, att, out, avgp, counts, scal);
  zq_kernel<<<2048, 256, 0, stream>>>(x, att, cbt, out, scal);
  finalize_kernel<<<1, 1024, 0, stream>>>(avgp, counts, scal, out);
}